// Round 2
// baseline (1543.315 us; speedup 1.0000x reference)
//
#include <hip/hip_runtime.h>

#define N_NODES 50000
#define N_EDGES 800000
#define IN_DIM  128
#define OUT_DIM 256
#define ROWS_PER_BLOCK 32
#define XSTRIDE 36  // >= ROWS_PER_BLOCK, and 36*4B = 144B (16B-aligned rows)

// ---------------------------------------------------------------------------
// Kernel 0: detect whether src/dst were staged as int32 or int64.
// Reference dtype is int64; harness doc implies int32 downcast. Values are
// < 50000 (< 2^31), so if the buffer is int64 every odd 32-bit word is 0.
// For int32 data the odd words are random indices (P(all zero) ~ 0).
// flag = 1 -> int64, 0 -> int32.
// ---------------------------------------------------------------------------
__global__ void probe_idx_dtype(const int* __restrict__ words,
                                int* __restrict__ flag) {
  __shared__ int cnt;
  if (threadIdx.x == 0) cnt = 0;
  __syncthreads();
  int j = 2 * (int)threadIdx.x + 1;  // odd words 1,3,...,511
  if (words[j] != 0) atomicAdd(&cnt, 1);
  __syncthreads();
  if (threadIdx.x == 0) *flag = (cnt == 0) ? 1 : 0;
}

// ---------------------------------------------------------------------------
// Kernel 1: edge scatter. 32 threads per edge; each thread float4-gathers
// from feat[src] and atomicAdds into msg[dst]. Lane 0 bumps degree.
// ---------------------------------------------------------------------------
__global__ __launch_bounds__(256) void edge_scatter(
    const float* __restrict__ feat, const int* __restrict__ src,
    const int* __restrict__ dst, float* __restrict__ msg,
    float* __restrict__ deg, const int* __restrict__ flag) {
  long tid = (long)blockIdx.x * blockDim.x + threadIdx.x;
  long e = tid >> 5;
  if (e >= N_EDGES) return;
  int lane = (int)(tid & 31);
  long off = (*flag) ? (e << 1) : e;  // int64: low word at 2*e (LE)
  int s = src[off];
  int d = dst[off];
  const float4 v =
      *reinterpret_cast<const float4*>(feat + (size_t)s * IN_DIM + lane * 4);
  float* m = msg + (size_t)d * IN_DIM + lane * 4;
  atomicAdd(m + 0, v.x);
  atomicAdd(m + 1, v.y);
  atomicAdd(m + 2, v.z);
  atomicAdd(m + 3, v.w);
  if (lane == 0) atomicAdd(deg + d, 1.0f);
}

// ---------------------------------------------------------------------------
// Kernel 2: fused (feat + msg/deg)*0.5 @ W with relu epilogue.
// 512 threads, 32 rows/block, full W (128 KiB) + xT (18 KiB) in LDS.
// Per-thread 4x4 register tile: per k, 1 ds_read_b128 (W, conflict-free
// lane-stride-16B) + 1 ds_read_b128 (xT, wave-uniform broadcast) + 16 FMA.
// ---------------------------------------------------------------------------
__global__ __launch_bounds__(512) void fused_gemm(
    const float* __restrict__ feat, const float* __restrict__ msg,
    const float* __restrict__ deg, const float* __restrict__ W,
    float* __restrict__ out) {
  __shared__ __align__(16) float Wlds[IN_DIM * OUT_DIM];   // 128 KiB
  __shared__ __align__(16) float xT[IN_DIM * XSTRIDE];     // 18 KiB
  __shared__ float s_rd[ROWS_PER_BLOCK];

  const int tid = threadIdx.x;
  const int row0 = blockIdx.x * ROWS_PER_BLOCK;

  // Per-row reciprocal degree.
  if (tid < ROWS_PER_BLOCK) {
    int row = row0 + tid;
    float dv = (row < N_NODES) ? deg[row] : 1.0f;
    s_rd[tid] = 1.0f / fmaxf(dv, 1.0f);
  }

  // Stage W: 32768 floats / 512 threads = 16 float4 per thread, coalesced.
#pragma unroll
  for (int p = 0; p < (IN_DIM * OUT_DIM) / (512 * 4); ++p) {
    int idx = (p * 512 + tid) * 4;
    *reinterpret_cast<float4*>(&Wlds[idx]) =
        *reinterpret_cast<const float4*>(&W[idx]);
  }
  __syncthreads();  // s_rd ready

  // Stage x transposed: xT[k*XSTRIDE + r] = 0.5*(feat + msg*rd).
#pragma unroll
  for (int p = 0; p < (ROWS_PER_BLOCK * IN_DIM) / 512; ++p) {
    int idx = p * 512 + tid;
    int k = idx & (IN_DIM - 1);
    int r = idx >> 7;
    int row = row0 + r;
    float val = 0.0f;
    if (row < N_NODES) {
      val = (feat[(size_t)row * IN_DIM + k] +
             msg[(size_t)row * IN_DIM + k] * s_rd[r]) * 0.5f;
    }
    xT[k * XSTRIDE + r] = val;  // max idx 127*36+31 = 4603 < 4608, in bounds
  }
  __syncthreads();

  const int cg = tid & 63;  // column group: cols cg*4 .. cg*4+3
  const int rg = tid >> 6;  // row group (wave-uniform): rows rg*4 .. rg*4+3

  float acc[4][4];
#pragma unroll
  for (int r = 0; r < 4; ++r)
#pragma unroll
    for (int c = 0; c < 4; ++c) acc[r][c] = 0.0f;

#pragma unroll 8
  for (int k = 0; k < IN_DIM; ++k) {
    float4 w = *reinterpret_cast<float4*>(&Wlds[k * OUT_DIM + cg * 4]);
    float4 xv = *reinterpret_cast<float4*>(&xT[k * XSTRIDE + rg * 4]);
    acc[0][0] += xv.x * w.x; acc[0][1] += xv.x * w.y;
    acc[0][2] += xv.x * w.z; acc[0][3] += xv.x * w.w;
    acc[1][0] += xv.y * w.x; acc[1][1] += xv.y * w.y;
    acc[1][2] += xv.y * w.z; acc[1][3] += xv.y * w.w;
    acc[2][0] += xv.z * w.x; acc[2][1] += xv.z * w.y;
    acc[2][2] += xv.z * w.z; acc[2][3] += xv.z * w.w;
    acc[3][0] += xv.w * w.x; acc[3][1] += xv.w * w.y;
    acc[3][2] += xv.w * w.z; acc[3][3] += xv.w * w.w;
  }

#pragma unroll
  for (int r = 0; r < 4; ++r) {
    int row = row0 + rg * 4 + r;
    if (row < N_NODES) {
      float4 o;
      o.x = fmaxf(acc[r][0], 0.0f);
      o.y = fmaxf(acc[r][1], 0.0f);
      o.z = fmaxf(acc[r][2], 0.0f);
      o.w = fmaxf(acc[r][3], 0.0f);
      *reinterpret_cast<float4*>(&out[(size_t)row * OUT_DIM + cg * 4]) = o;
    }
  }
}

extern "C" void kernel_launch(void* const* d_in, const int* in_sizes, int n_in,
                              void* d_out, int out_size, void* d_ws,
                              size_t ws_size, hipStream_t stream) {
  const float* feat = (const float*)d_in[0];
  const float* W = (const float*)d_in[1];
  const int* src = (const int*)d_in[2];
  const int* dst = (const int*)d_in[3];
  float* out = (float*)d_out;

  float* msg = (float*)d_ws;                       // 50000*128 f32 = 25.6 MB
  float* deg = msg + (size_t)N_NODES * IN_DIM;     // 50000 f32
  int* flag = (int*)(deg + N_NODES);               // 1 int

  size_t zero_bytes = ((size_t)N_NODES * IN_DIM + N_NODES) * sizeof(float);
  hipMemsetAsync(d_ws, 0, zero_bytes, stream);

  probe_idx_dtype<<<1, 256, 0, stream>>>(src, flag);

  {
    long total = (long)N_EDGES * 32;
    int blocks = (int)((total + 255) / 256);
    edge_scatter<<<blocks, 256, 0, stream>>>(feat, src, dst, msg, deg, flag);
  }
  {
    int blocks = (N_NODES + ROWS_PER_BLOCK - 1) / ROWS_PER_BLOCK;
    fused_gemm<<<blocks, 512, 0, stream>>>(feat, msg, deg, W, out);
  }
}

// Round 3
// 299.438 us; speedup vs baseline: 5.1540x; 5.1540x over previous
//
#include <hip/hip_runtime.h>
#include <hip/hip_fp16.h>

#define N_NODES 50000
#define N_EDGES 800000
#define IN_DIM  128
#define OUT_DIM 256
#define ROWS_PER_BLOCK 32
#define XSTRIDE 36  // floats; 144B rows, 16B-aligned for the b128 broadcast reads
#define SCAN_BLOCKS ((N_NODES + 255) / 256)  // 196

// ---------------------------------------------------------------------------
// Kernel 0: int32 vs int64 index dtype probe (values < 2^31 -> int64 has all
// odd 32-bit words zero). flag = 1 -> int64, 0 -> int32.
// ---------------------------------------------------------------------------
__global__ void probe_idx_dtype(const int* __restrict__ words,
                                int* __restrict__ flag) {
  __shared__ int cnt;
  if (threadIdx.x == 0) cnt = 0;
  __syncthreads();
  int j = 2 * (int)threadIdx.x + 1;
  if (words[j] != 0) atomicAdd(&cnt, 1);
  __syncthreads();
  if (threadIdx.x == 0) *flag = (cnt == 0) ? 1 : 0;
}

__device__ __forceinline__ long idx_off(long e, int flag) {
  return flag ? (e << 1) : e;
}

// ---------------------------------------------------------------------------
// CSR build: histogram of dst, 3-kernel exclusive scan, scatter src by dst.
// ---------------------------------------------------------------------------
__global__ __launch_bounds__(256) void hist_kernel(
    const int* __restrict__ dst, const int* __restrict__ flag,
    int* __restrict__ hist) {
  int e = blockIdx.x * 256 + threadIdx.x;
  if (e >= N_EDGES) return;
  int d = dst[idx_off(e, *flag)];
  atomicAdd(&hist[d], 1);
}

__global__ __launch_bounds__(256) void scan_block(
    const int* __restrict__ hist, int* __restrict__ pre,
    int* __restrict__ bsum) {
  __shared__ int s[256];
  int tid = threadIdx.x;
  int i = blockIdx.x * 256 + tid;
  int v = (i < N_NODES) ? hist[i] : 0;
  s[tid] = v;
  __syncthreads();
  for (int off = 1; off < 256; off <<= 1) {
    int t = (tid >= off) ? s[tid - off] : 0;
    __syncthreads();
    s[tid] += t;
    __syncthreads();
  }
  if (i < N_NODES) pre[i] = s[tid] - v;  // exclusive within block
  if (tid == 255) bsum[blockIdx.x] = s[255];
}

__global__ __launch_bounds__(256) void scan_tops(int* __restrict__ bsum) {
  __shared__ int s[256];
  int tid = threadIdx.x;
  int v = (tid < SCAN_BLOCKS) ? bsum[tid] : 0;
  s[tid] = v;
  __syncthreads();
  for (int off = 1; off < 256; off <<= 1) {
    int t = (tid >= off) ? s[tid - off] : 0;
    __syncthreads();
    s[tid] += t;
    __syncthreads();
  }
  if (tid < SCAN_BLOCKS) bsum[tid] = s[tid] - v;  // exclusive
}

__global__ __launch_bounds__(256) void scan_add(
    const int* __restrict__ pre, const int* __restrict__ bsum,
    int* __restrict__ row_start) {
  int i = blockIdx.x * 256 + threadIdx.x;
  if (i < N_NODES) row_start[i] = pre[i] + bsum[blockIdx.x];
  if (i == 0) row_start[N_NODES] = N_EDGES;
}

__global__ __launch_bounds__(256) void scatter_kernel(
    const int* __restrict__ src, const int* __restrict__ dst,
    const int* __restrict__ flag, const int* __restrict__ row_start,
    int* __restrict__ cursor, int* __restrict__ esrc) {
  int e = blockIdx.x * 256 + threadIdx.x;
  if (e >= N_EDGES) return;
  int f = *flag;
  int d = dst[idx_off(e, f)];
  int s = src[idx_off(e, f)];
  int pos = row_start[d] + atomicAdd(&cursor[d], 1);
  esrc[pos] = s;
}

// ---------------------------------------------------------------------------
// Aggregation (pull): one wave per node. Lane handles 2 columns (float2).
// x[node][k] = (feat[node][k] + mean_neigh[k]) * 0.5, stored fp16.
// ---------------------------------------------------------------------------
__global__ __launch_bounds__(256) void aggregate_kernel(
    const float* __restrict__ feat, const int* __restrict__ esrc,
    const int* __restrict__ row_start, __half2* __restrict__ x) {
  int node = blockIdx.x * 4 + ((int)threadIdx.x >> 6);
  int lane = (int)threadIdx.x & 63;
  if (node >= N_NODES) return;
  int rs = row_start[node];
  int re = row_start[node + 1];

  float2 a0 = {0.f, 0.f}, a1 = {0.f, 0.f};
  int e = rs;
  for (; e + 1 < re; e += 2) {
    int s0 = esrc[e];
    int s1 = esrc[e + 1];
    float2 v0 = *reinterpret_cast<const float2*>(
        feat + (size_t)s0 * IN_DIM + lane * 2);
    float2 v1 = *reinterpret_cast<const float2*>(
        feat + (size_t)s1 * IN_DIM + lane * 2);
    a0.x += v0.x; a0.y += v0.y;
    a1.x += v1.x; a1.y += v1.y;
  }
  if (e < re) {
    int s0 = esrc[e];
    float2 v0 = *reinterpret_cast<const float2*>(
        feat + (size_t)s0 * IN_DIM + lane * 2);
    a0.x += v0.x; a0.y += v0.y;
  }
  float deg = (float)(re - rs);
  float rdeg = (deg > 0.f) ? 1.0f / deg : 0.0f;
  float2 f = *reinterpret_cast<const float2*>(
      feat + (size_t)node * IN_DIM + lane * 2);
  float x0 = (f.x + (a0.x + a1.x) * rdeg) * 0.5f;
  float x1 = (f.y + (a0.y + a1.y) * rdeg) * 0.5f;
  x[(size_t)node * (IN_DIM / 2) + lane] = __floats2half2_rn(x0, x1);
}

// ---------------------------------------------------------------------------
// GEMM: relu(x @ W). 512 threads, 32 rows/block, W (128 KiB) + xT in LDS.
// Hot loop per k: ds_read_b128 (W, conflict-free) + ds_read_b128 (xT,
// wave-uniform broadcast) + 16 v_fma_f32.
// ---------------------------------------------------------------------------
__global__ __launch_bounds__(512) void fused_gemm(
    const __half2* __restrict__ x, const float* __restrict__ W,
    float* __restrict__ out) {
  __shared__ __align__(16) float Wlds[IN_DIM * OUT_DIM];  // 128 KiB
  __shared__ __align__(16) float xT[IN_DIM * XSTRIDE];    // 18 KiB

  const int tid = threadIdx.x;
  const int row0 = blockIdx.x * ROWS_PER_BLOCK;

  // Stage W: 16 float4 per thread, coalesced, conflict-free.
#pragma unroll
  for (int p = 0; p < (IN_DIM * OUT_DIM) / (512 * 4); ++p) {
    int idx = (p * 512 + tid) * 4;
    *reinterpret_cast<float4*>(&Wlds[idx]) =
        *reinterpret_cast<const float4*>(&W[idx]);
  }

  // Stage x (fp16) transposed into xT (f32). Block region of x is 8 KiB
  // contiguous -> L1-resident. Lane->row mapping keeps ds_write conflict-free.
#pragma unroll
  for (int p = 0; p < (ROWS_PER_BLOCK * IN_DIM / 2) / 512; ++p) {  // 4 iters
    int idx = p * 512 + tid;
    int r = idx & 31;
    int kk = idx >> 5;  // half2 index, 0..63
    int row = row0 + r;
    float2 v = {0.f, 0.f};
    if (row < N_NODES) v = __half22float2(x[(size_t)row * (IN_DIM / 2) + kk]);
    xT[(2 * kk) * XSTRIDE + r] = v.x;
    xT[(2 * kk + 1) * XSTRIDE + r] = v.y;
  }
  __syncthreads();

  const int cg = tid & 63;  // cols cg*4 .. cg*4+3
  const int rg = tid >> 6;  // rows rg*4 .. rg*4+3 (wave-uniform)

  float acc[4][4];
#pragma unroll
  for (int r = 0; r < 4; ++r)
#pragma unroll
    for (int c = 0; c < 4; ++c) acc[r][c] = 0.0f;

#pragma unroll 8
  for (int k = 0; k < IN_DIM; ++k) {
    float4 w = *reinterpret_cast<float4*>(&Wlds[k * OUT_DIM + cg * 4]);
    float4 xv = *reinterpret_cast<float4*>(&xT[k * XSTRIDE + rg * 4]);
    acc[0][0] += xv.x * w.x; acc[0][1] += xv.x * w.y;
    acc[0][2] += xv.x * w.z; acc[0][3] += xv.x * w.w;
    acc[1][0] += xv.y * w.x; acc[1][1] += xv.y * w.y;
    acc[1][2] += xv.y * w.z; acc[1][3] += xv.y * w.w;
    acc[2][0] += xv.z * w.x; acc[2][1] += xv.z * w.y;
    acc[2][2] += xv.z * w.z; acc[2][3] += xv.z * w.w;
    acc[3][0] += xv.w * w.x; acc[3][1] += xv.w * w.y;
    acc[3][2] += xv.w * w.z; acc[3][3] += xv.w * w.w;
  }

#pragma unroll
  for (int r = 0; r < 4; ++r) {
    int row = row0 + rg * 4 + r;
    if (row < N_NODES) {
      float4 o;
      o.x = fmaxf(acc[r][0], 0.0f);
      o.y = fmaxf(acc[r][1], 0.0f);
      o.z = fmaxf(acc[r][2], 0.0f);
      o.w = fmaxf(acc[r][3], 0.0f);
      *reinterpret_cast<float4*>(&out[(size_t)row * OUT_DIM + cg * 4]) = o;
    }
  }
}

extern "C" void kernel_launch(void* const* d_in, const int* in_sizes, int n_in,
                              void* d_out, int out_size, void* d_ws,
                              size_t ws_size, hipStream_t stream) {
  const float* feat = (const float*)d_in[0];
  const float* W = (const float*)d_in[1];
  const int* src = (const int*)d_in[2];
  const int* dst = (const int*)d_in[3];
  float* out = (float*)d_out;

  // Workspace layout (~16.6 MB total; proven ws >= 25.8 MB).
  char* p = (char*)d_ws;
  __half2* x = (__half2*)p;            p += (size_t)N_NODES * IN_DIM * 2;  // 12.8 MB
  int* esrc = (int*)p;                 p += (size_t)N_EDGES * 4;           // 3.2 MB
  int* hist = (int*)p;                 p += (size_t)N_NODES * 4;
  int* cursor = (int*)p;               p += (size_t)N_NODES * 4;
  int* pre = (int*)p;                  p += (size_t)N_NODES * 4;
  int* row_start = (int*)p;            p += (size_t)(N_NODES + 1) * 4;
  int* bsum = (int*)p;                 p += 256 * 4;
  int* flag = (int*)p;

  // Zero hist + cursor (contiguous, 400 KB).
  hipMemsetAsync(hist, 0, (size_t)2 * N_NODES * 4, stream);

  probe_idx_dtype<<<1, 256, 0, stream>>>(src, flag);

  int eblocks = (N_EDGES + 255) / 256;  // 3125
  hist_kernel<<<eblocks, 256, 0, stream>>>(dst, flag, hist);
  scan_block<<<SCAN_BLOCKS, 256, 0, stream>>>(hist, pre, bsum);
  scan_tops<<<1, 256, 0, stream>>>(bsum);
  scan_add<<<SCAN_BLOCKS, 256, 0, stream>>>(pre, bsum, row_start);
  scatter_kernel<<<eblocks, 256, 0, stream>>>(src, dst, flag, row_start,
                                              cursor, esrc);
  aggregate_kernel<<<(N_NODES + 3) / 4, 256, 0, stream>>>(feat, esrc,
                                                          row_start, x);
  fused_gemm<<<(N_NODES + ROWS_PER_BLOCK - 1) / ROWS_PER_BLOCK, 512, 0,
               stream>>>(x, W, out);
}

// Round 5
// 248.803 us; speedup vs baseline: 6.2030x; 1.2035x over previous
//
#include <hip/hip_runtime.h>
#include <hip/hip_fp16.h>

#define N_NODES 50000
#define N_EDGES 800000
#define IN_DIM  128
#define OUT_DIM 256
#define SCAN_BLOCKS ((N_NODES + 255) / 256)  // 196
#define WT_STRIDE 136  // f16 elems; 272B rows -> uniform bank spread, 16B-aligned

typedef _Float16 f16x8 __attribute__((ext_vector_type(8)));
typedef _Float16 f16x4 __attribute__((ext_vector_type(4)));
typedef float f32x4 __attribute__((ext_vector_type(4)));

// ---------------------------------------------------------------------------
// Kernel 0: int32 vs int64 index dtype probe. flag=1 -> int64, 0 -> int32.
// ---------------------------------------------------------------------------
__global__ void probe_idx_dtype(const int* __restrict__ words,
                                int* __restrict__ flag) {
  __shared__ int cnt;
  if (threadIdx.x == 0) cnt = 0;
  __syncthreads();
  int j = 2 * (int)threadIdx.x + 1;
  if (words[j] != 0) atomicAdd(&cnt, 1);
  __syncthreads();
  if (threadIdx.x == 0) *flag = (cnt == 0) ? 1 : 0;
}

__device__ __forceinline__ long idx_off(long e, int flag) {
  return flag ? (e << 1) : e;
}

// ---------------------------------------------------------------------------
// CSR build: histogram, 3-kernel exclusive scan, scatter (proven round 3).
// ---------------------------------------------------------------------------
__global__ __launch_bounds__(256) void hist_kernel(
    const int* __restrict__ dst, const int* __restrict__ flag,
    int* __restrict__ hist) {
  int e = blockIdx.x * 256 + threadIdx.x;
  if (e >= N_EDGES) return;
  int d = dst[idx_off(e, *flag)];
  atomicAdd(&hist[d], 1);
}

__global__ __launch_bounds__(256) void scan_block(
    const int* __restrict__ hist, int* __restrict__ pre,
    int* __restrict__ bsum) {
  __shared__ int s[256];
  int tid = threadIdx.x;
  int i = blockIdx.x * 256 + tid;
  int v = (i < N_NODES) ? hist[i] : 0;
  s[tid] = v;
  __syncthreads();
  for (int off = 1; off < 256; off <<= 1) {
    int t = (tid >= off) ? s[tid - off] : 0;
    __syncthreads();
    s[tid] += t;
    __syncthreads();
  }
  if (i < N_NODES) pre[i] = s[tid] - v;
  if (tid == 255) bsum[blockIdx.x] = s[255];
}

__global__ __launch_bounds__(256) void scan_tops(int* __restrict__ bsum) {
  __shared__ int s[256];
  int tid = threadIdx.x;
  int v = (tid < SCAN_BLOCKS) ? bsum[tid] : 0;
  s[tid] = v;
  __syncthreads();
  for (int off = 1; off < 256; off <<= 1) {
    int t = (tid >= off) ? s[tid - off] : 0;
    __syncthreads();
    s[tid] += t;
    __syncthreads();
  }
  if (tid < SCAN_BLOCKS) bsum[tid] = s[tid] - v;
}

__global__ __launch_bounds__(256) void scan_add(
    const int* __restrict__ pre, const int* __restrict__ bsum,
    int* __restrict__ row_start) {
  int i = blockIdx.x * 256 + threadIdx.x;
  if (i < N_NODES) row_start[i] = pre[i] + bsum[blockIdx.x];
  if (i == 0) row_start[N_NODES] = N_EDGES;
}

__global__ __launch_bounds__(256) void scatter_kernel(
    const int* __restrict__ src, const int* __restrict__ dst,
    const int* __restrict__ flag, const int* __restrict__ row_start,
    int* __restrict__ cursor, int* __restrict__ esrc) {
  int e = blockIdx.x * 256 + threadIdx.x;
  if (e >= N_EDGES) return;
  int f = *flag;
  int d = dst[idx_off(e, f)];
  int s = src[idx_off(e, f)];
  int pos = row_start[d] + atomicAdd(&cursor[d], 1);
  esrc[pos] = s;
}

// ---------------------------------------------------------------------------
// feat f32 -> f16 cast (only used when workspace allows the fast path).
// ---------------------------------------------------------------------------
__global__ __launch_bounds__(256) void cast_feat(
    const float* __restrict__ feat, __half* __restrict__ feat16) {
  size_t i = ((size_t)blockIdx.x * 256 + threadIdx.x) * 8;
  float4 v0 = *reinterpret_cast<const float4*>(feat + i);
  float4 v1 = *reinterpret_cast<const float4*>(feat + i + 4);
  __half2 h[4];
  h[0] = __floats2half2_rn(v0.x, v0.y);
  h[1] = __floats2half2_rn(v0.z, v0.w);
  h[2] = __floats2half2_rn(v1.x, v1.y);
  h[3] = __floats2half2_rn(v1.z, v1.w);
  *reinterpret_cast<float4*>(feat16 + i) = *reinterpret_cast<float4*>(h);
}

// ---------------------------------------------------------------------------
// Aggregation (pull), one wave per node. x = 0.5*(feat + mean_neigh), fp16.
// f32 variant (proven) and f16-gather variant (half the gather bytes).
// ---------------------------------------------------------------------------
__global__ __launch_bounds__(256) void aggregate_f32(
    const float* __restrict__ feat, const int* __restrict__ esrc,
    const int* __restrict__ row_start, __half2* __restrict__ x) {
  int node = blockIdx.x * 4 + ((int)threadIdx.x >> 6);
  int lane = (int)threadIdx.x & 63;
  if (node >= N_NODES) return;
  int rs = row_start[node];
  int re = row_start[node + 1];
  float2 a0 = {0.f, 0.f}, a1 = {0.f, 0.f};
  int e = rs;
  for (; e + 1 < re; e += 2) {
    int s0 = esrc[e];
    int s1 = esrc[e + 1];
    float2 v0 = *reinterpret_cast<const float2*>(feat + (size_t)s0 * IN_DIM + lane * 2);
    float2 v1 = *reinterpret_cast<const float2*>(feat + (size_t)s1 * IN_DIM + lane * 2);
    a0.x += v0.x; a0.y += v0.y;
    a1.x += v1.x; a1.y += v1.y;
  }
  if (e < re) {
    int s0 = esrc[e];
    float2 v0 = *reinterpret_cast<const float2*>(feat + (size_t)s0 * IN_DIM + lane * 2);
    a0.x += v0.x; a0.y += v0.y;
  }
  float deg = (float)(re - rs);
  float rdeg = (deg > 0.f) ? 1.0f / deg : 0.0f;
  float2 f = *reinterpret_cast<const float2*>(feat + (size_t)node * IN_DIM + lane * 2);
  float x0 = (f.x + (a0.x + a1.x) * rdeg) * 0.5f;
  float x1 = (f.y + (a0.y + a1.y) * rdeg) * 0.5f;
  x[(size_t)node * (IN_DIM / 2) + lane] = __floats2half2_rn(x0, x1);
}

__global__ __launch_bounds__(256) void aggregate_f16(
    const float* __restrict__ feat, const __half* __restrict__ feat16,
    const int* __restrict__ esrc, const int* __restrict__ row_start,
    __half2* __restrict__ x) {
  int node = blockIdx.x * 4 + ((int)threadIdx.x >> 6);
  int lane = (int)threadIdx.x & 63;
  if (node >= N_NODES) return;
  int rs = row_start[node];
  int re = row_start[node + 1];
  float2 a0 = {0.f, 0.f}, a1 = {0.f, 0.f};
  int e = rs;
  for (; e + 1 < re; e += 2) {
    int s0 = esrc[e];
    int s1 = esrc[e + 1];
    __half2 h0 = *reinterpret_cast<const __half2*>(feat16 + (size_t)s0 * IN_DIM + lane * 2);
    __half2 h1 = *reinterpret_cast<const __half2*>(feat16 + (size_t)s1 * IN_DIM + lane * 2);
    float2 v0 = __half22float2(h0);
    float2 v1 = __half22float2(h1);
    a0.x += v0.x; a0.y += v0.y;
    a1.x += v1.x; a1.y += v1.y;
  }
  if (e < re) {
    __half2 h0 = *reinterpret_cast<const __half2*>(feat16 + (size_t)esrc[e] * IN_DIM + lane * 2);
    float2 v0 = __half22float2(h0);
    a0.x += v0.x; a0.y += v0.y;
  }
  float deg = (float)(re - rs);
  float rdeg = (deg > 0.f) ? 1.0f / deg : 0.0f;
  float2 f = *reinterpret_cast<const float2*>(feat + (size_t)node * IN_DIM + lane * 2);
  float x0 = (f.x + (a0.x + a1.x) * rdeg) * 0.5f;
  float x1 = (f.y + (a0.y + a1.y) * rdeg) * 0.5f;
  x[(size_t)node * (IN_DIM / 2) + lane] = __floats2half2_rn(x0, x1);
}

// ---------------------------------------------------------------------------
// MFMA GEMM: out = relu(x @ W), x fp16 [50000x128], W f32->f16 [128x256].
// Block 256 (4 waves), 128 rows/block. W transposed in LDS (WT[n][k], stride
// 136 f16): B-frag = 1 ds_read_b128, uniform bank load. Per wave: 2 row-tiles
// (B-frag reuse x2), 16 n-tiles x 4 k-tiles -> 128 MFMA : 64 ds_read_b128.
// C/D layout (m89-verified): col=lane&15, row=(lane>>4)*4+reg.
// ---------------------------------------------------------------------------
__global__ __launch_bounds__(256) void mfma_gemm(
    const _Float16* __restrict__ x, const float* __restrict__ W,
    float* __restrict__ out) {
  __shared__ _Float16 WT[OUT_DIM * WT_STRIDE];  // 256*136*2 = 68 KiB

  const int tid = threadIdx.x;
  // Stage WT[n][k] = (f16)W[k][n]; global reads coalesced (1 KiB per k-row).
  {
    const int n = tid;
#pragma unroll
    for (int k = 0; k < IN_DIM; k += 4) {
      f16x4 v;
      v.x = (_Float16)W[(k + 0) * OUT_DIM + n];
      v.y = (_Float16)W[(k + 1) * OUT_DIM + n];
      v.z = (_Float16)W[(k + 2) * OUT_DIM + n];
      v.w = (_Float16)W[(k + 3) * OUT_DIM + n];
      *reinterpret_cast<f16x4*>(&WT[n * WT_STRIDE + k]) = v;
    }
  }
  __syncthreads();

  const int wave = tid >> 6;
  const int lane = tid & 63;
  const int m = lane & 15;   // A row-in-tile / B col-in-tile / C col
  const int g = lane >> 4;   // k-chunk group (any consistent bijection works)
  const long row_base = (long)blockIdx.x * 128 + wave * 32;

  // A fragments: 2 row-tiles x 4 k-tiles, 16B contiguous per lane.
  f16x8 a[2][4];
#pragma unroll
  for (int rt = 0; rt < 2; ++rt) {
    long row = row_base + rt * 16 + m;
#pragma unroll
    for (int kt = 0; kt < 4; ++kt) {
      if (row < N_NODES) {
        a[rt][kt] = *reinterpret_cast<const f16x8*>(
            x + row * IN_DIM + kt * 32 + g * 8);
      } else {
        a[rt][kt] = f16x8{};
      }
    }
  }

#pragma unroll
  for (int nt = 0; nt < 16; ++nt) {
    f16x8 b[4];
#pragma unroll
    for (int kt = 0; kt < 4; ++kt) {
      b[kt] = *reinterpret_cast<const f16x8*>(
          &WT[(nt * 16 + m) * WT_STRIDE + kt * 32 + g * 8]);
    }
    f32x4 acc0 = {0.f, 0.f, 0.f, 0.f};
    f32x4 acc1 = {0.f, 0.f, 0.f, 0.f};
#pragma unroll
    for (int kt = 0; kt < 4; ++kt) {
      acc0 = __builtin_amdgcn_mfma_f32_16x16x32_f16(a[0][kt], b[kt], acc0, 0, 0, 0);
      acc1 = __builtin_amdgcn_mfma_f32_16x16x32_f16(a[1][kt], b[kt], acc1, 0, 0, 0);
    }
    const int col = nt * 16 + m;
#pragma unroll
    for (int j = 0; j < 4; ++j) {
      long r0 = row_base + g * 4 + j;
      long r1 = row_base + 16 + g * 4 + j;
      if (r0 < N_NODES) out[r0 * OUT_DIM + col] = fmaxf(acc0[j], 0.f);
      if (r1 < N_NODES) out[r1 * OUT_DIM + col] = fmaxf(acc1[j], 0.f);
    }
  }
}

extern "C" void kernel_launch(void* const* d_in, const int* in_sizes, int n_in,
                              void* d_out, int out_size, void* d_ws,
                              size_t ws_size, hipStream_t stream) {
  const float* feat = (const float*)d_in[0];
  const float* W = (const float*)d_in[1];
  const int* src = (const int*)d_in[2];
  const int* dst = (const int*)d_in[3];
  float* out = (float*)d_out;

  // Workspace layout. Base: 16.8 MB (proven ws >= 25.8 MB). feat16 fast path
  // needs 29.7 MB total -> gated on ws_size (constant across calls).
  char* p = (char*)d_ws;
  __half* x = (__half*)p;    p += (size_t)N_NODES * IN_DIM * 2;  // 12.8 MB
  int* esrc = (int*)p;       p += (size_t)N_EDGES * 4;           // 3.2 MB
  int* hist = (int*)p;       p += (size_t)N_NODES * 4;
  int* cursor = (int*)p;     p += (size_t)N_NODES * 4;
  int* pre = (int*)p;        p += (size_t)N_NODES * 4;
  int* row_start = (int*)p;  p += (size_t)(N_NODES + 1) * 4;
  int* bsum = (int*)p;       p += 256 * 4;
  int* flag = (int*)p;       p += 64;  // keep 16B alignment after
  __half* feat16 = (__half*)p;
  size_t need_f16 = ((char*)feat16 - (char*)d_ws) +
                    (size_t)N_NODES * IN_DIM * 2;
  const bool f16_path = (ws_size >= need_f16);

  hipMemsetAsync(hist, 0, (size_t)2 * N_NODES * 4, stream);  // hist + cursor

  probe_idx_dtype<<<1, 256, 0, stream>>>(src, flag);

  int eblocks = (N_EDGES + 255) / 256;  // 3125
  hist_kernel<<<eblocks, 256, 0, stream>>>(dst, flag, hist);
  scan_block<<<SCAN_BLOCKS, 256, 0, stream>>>(hist, pre, bsum);
  scan_tops<<<1, 256, 0, stream>>>(bsum);
  scan_add<<<SCAN_BLOCKS, 256, 0, stream>>>(pre, bsum, row_start);
  scatter_kernel<<<eblocks, 256, 0, stream>>>(src, dst, flag, row_start,
                                              cursor, esrc);
  if (f16_path) {
    cast_feat<<<(N_NODES * IN_DIM) / (256 * 8), 256, 0, stream>>>(feat, feat16);
    aggregate_f16<<<(N_NODES + 3) / 4, 256, 0, stream>>>(feat, feat16, esrc,
                                                         row_start,
                                                         (__half2*)x);
  } else {
    aggregate_f32<<<(N_NODES + 3) / 4, 256, 0, stream>>>(feat, esrc, row_start,
                                                         (__half2*)x);
  }
  mfma_gemm<<<(N_NODES + 127) / 128, 256, 0, stream>>>(
      (const _Float16*)x, W, out);
}

// Round 6
// 210.069 us; speedup vs baseline: 7.3467x; 1.1844x over previous
//
#include <hip/hip_runtime.h>
#include <hip/hip_fp16.h>

#define N_NODES 50000
#define N_EDGES 800000
#define IN_DIM  128
#define OUT_DIM 256
#define SCAN_BLOCKS ((N_NODES + 255) / 256)  // 196
#define WT_STRIDE 136  // f16 elems; 272B rows -> uniform bank spread, 16B-aligned

typedef _Float16 f16x8 __attribute__((ext_vector_type(8)));
typedef _Float16 f16x4 __attribute__((ext_vector_type(4)));
typedef float f32x4 __attribute__((ext_vector_type(4)));

// ---------------------------------------------------------------------------
// Uniform int64-vs-int32 detection, callable per block (no separate dispatch).
// Values < 2^31, so int64 staging => odd 32-bit words of the first 16 entries
// are all zero. Addresses are wave-uniform -> scalar loads, L2-hot.
// ---------------------------------------------------------------------------
__device__ __forceinline__ int detect_i64(const int* __restrict__ idx) {
  int orv = 0;
#pragma unroll
  for (int j = 1; j < 32; j += 2) orv |= idx[j];
  return orv == 0;
}

// ---------------------------------------------------------------------------
// Kernel 1: dst histogram + per-edge slot (atomic return value) + f32->f16
// feat cast fused (same 3125x256 grid; streaming cast hides atomic latency).
// ---------------------------------------------------------------------------
__global__ __launch_bounds__(256) void hist_cast(
    const int* __restrict__ dst, const float* __restrict__ feat,
    __half* __restrict__ feat16, int* __restrict__ hist,
    int* __restrict__ slot) {
  const int f = detect_i64(dst);
  const int e = blockIdx.x * 256 + threadIdx.x;  // grid exactly covers N_EDGES
  const int d = dst[f ? 2 * (long)e : (long)e];
  slot[e] = atomicAdd(&hist[d], 1);

  if (feat16 != nullptr) {
    size_t i = (size_t)e * 8;
    float4 v0 = *reinterpret_cast<const float4*>(feat + i);
    float4 v1 = *reinterpret_cast<const float4*>(feat + i + 4);
    __half2 h[4];
    h[0] = __floats2half2_rn(v0.x, v0.y);
    h[1] = __floats2half2_rn(v0.z, v0.w);
    h[2] = __floats2half2_rn(v1.x, v1.y);
    h[3] = __floats2half2_rn(v1.z, v1.w);
    *reinterpret_cast<float4*>(feat16 + i) = *reinterpret_cast<float4*>(h);
  }
}

// ---------------------------------------------------------------------------
// Kernel 2: per-block exclusive scan of hist into row_start (in place) + bsum.
// ---------------------------------------------------------------------------
__global__ __launch_bounds__(256) void scan_block(
    const int* __restrict__ hist, int* __restrict__ row_start,
    int* __restrict__ bsum) {
  __shared__ int s[256];
  int tid = threadIdx.x;
  int i = blockIdx.x * 256 + tid;
  int v = (i < N_NODES) ? hist[i] : 0;
  s[tid] = v;
  __syncthreads();
  for (int off = 1; off < 256; off <<= 1) {
    int t = (tid >= off) ? s[tid - off] : 0;
    __syncthreads();
    s[tid] += t;
    __syncthreads();
  }
  if (i < N_NODES) row_start[i] = s[tid] - v;
  if (tid == 255) bsum[blockIdx.x] = s[255];
}

// ---------------------------------------------------------------------------
// Kernel 3: add block prefix (each block redundantly reduces bsum[0..bid)).
// ---------------------------------------------------------------------------
__global__ __launch_bounds__(256) void scan_add(
    const int* __restrict__ bsum, int* __restrict__ row_start) {
  __shared__ int sb[256];
  int tid = threadIdx.x;
  sb[tid] = (tid < (int)blockIdx.x) ? bsum[tid] : 0;  // blockIdx.x <= 195
  __syncthreads();
  for (int off = 128; off > 0; off >>= 1) {
    if (tid < off) sb[tid] += sb[tid + off];
    __syncthreads();
  }
  int i = blockIdx.x * 256 + tid;
  if (i < N_NODES) row_start[i] += sb[0];
  if (i == 0) row_start[N_NODES] = N_EDGES;
}

// ---------------------------------------------------------------------------
// Kernel 4: scatter src into dst-sorted esrc (atomic-free: pos from slot).
// ---------------------------------------------------------------------------
__global__ __launch_bounds__(256) void scatter_kernel(
    const int* __restrict__ src, const int* __restrict__ dst,
    const int* __restrict__ row_start, const int* __restrict__ slot,
    int* __restrict__ esrc) {
  const int f = detect_i64(src);
  const int e = blockIdx.x * 256 + threadIdx.x;
  long off = f ? 2 * (long)e : (long)e;
  int d = dst[off];
  int s = src[off];
  esrc[row_start[d] + slot[e]] = s;
}

// ---------------------------------------------------------------------------
// Kernel 5: pull aggregation, one wave per node, unroll-4 for MLP.
// x = 0.5*(feat + mean_neigh), stored fp16. Self term from f32 feat.
// ---------------------------------------------------------------------------
__global__ __launch_bounds__(256) void aggregate_f16(
    const float* __restrict__ feat, const __half* __restrict__ feat16,
    const int* __restrict__ esrc, const int* __restrict__ row_start,
    __half2* __restrict__ x) {
  int node = blockIdx.x * 4 + ((int)threadIdx.x >> 6);
  int lane = (int)threadIdx.x & 63;
  if (node >= N_NODES) return;
  int rs = row_start[node];
  int re = row_start[node + 1];
  float2 a0 = {0.f, 0.f}, a1 = {0.f, 0.f}, a2 = {0.f, 0.f}, a3 = {0.f, 0.f};
  int e = rs;
  for (; e + 3 < re; e += 4) {
    int s0 = esrc[e + 0];
    int s1 = esrc[e + 1];
    int s2 = esrc[e + 2];
    int s3 = esrc[e + 3];
    float2 v0 = __half22float2(*reinterpret_cast<const __half2*>(
        feat16 + (size_t)s0 * IN_DIM + lane * 2));
    float2 v1 = __half22float2(*reinterpret_cast<const __half2*>(
        feat16 + (size_t)s1 * IN_DIM + lane * 2));
    float2 v2 = __half22float2(*reinterpret_cast<const __half2*>(
        feat16 + (size_t)s2 * IN_DIM + lane * 2));
    float2 v3 = __half22float2(*reinterpret_cast<const __half2*>(
        feat16 + (size_t)s3 * IN_DIM + lane * 2));
    a0.x += v0.x; a0.y += v0.y;
    a1.x += v1.x; a1.y += v1.y;
    a2.x += v2.x; a2.y += v2.y;
    a3.x += v3.x; a3.y += v3.y;
  }
  for (; e < re; ++e) {
    float2 v0 = __half22float2(*reinterpret_cast<const __half2*>(
        feat16 + (size_t)esrc[e] * IN_DIM + lane * 2));
    a0.x += v0.x; a0.y += v0.y;
  }
  float deg = (float)(re - rs);
  float rdeg = (deg > 0.f) ? 1.0f / deg : 0.0f;
  float2 f = *reinterpret_cast<const float2*>(
      feat + (size_t)node * IN_DIM + lane * 2);
  float x0 = (f.x + (a0.x + a1.x + a2.x + a3.x) * rdeg) * 0.5f;
  float x1 = (f.y + (a0.y + a1.y + a2.y + a3.y) * rdeg) * 0.5f;
  x[(size_t)node * (IN_DIM / 2) + lane] = __floats2half2_rn(x0, x1);
}

// f32-gather fallback (only if workspace can't hold feat16 — not expected).
__global__ __launch_bounds__(256) void aggregate_f32(
    const float* __restrict__ feat, const int* __restrict__ esrc,
    const int* __restrict__ row_start, __half2* __restrict__ x) {
  int node = blockIdx.x * 4 + ((int)threadIdx.x >> 6);
  int lane = (int)threadIdx.x & 63;
  if (node >= N_NODES) return;
  int rs = row_start[node];
  int re = row_start[node + 1];
  float2 a0 = {0.f, 0.f}, a1 = {0.f, 0.f};
  int e = rs;
  for (; e + 1 < re; e += 2) {
    float2 v0 = *reinterpret_cast<const float2*>(
        feat + (size_t)esrc[e] * IN_DIM + lane * 2);
    float2 v1 = *reinterpret_cast<const float2*>(
        feat + (size_t)esrc[e + 1] * IN_DIM + lane * 2);
    a0.x += v0.x; a0.y += v0.y;
    a1.x += v1.x; a1.y += v1.y;
  }
  if (e < re) {
    float2 v0 = *reinterpret_cast<const float2*>(
        feat + (size_t)esrc[e] * IN_DIM + lane * 2);
    a0.x += v0.x; a0.y += v0.y;
  }
  float deg = (float)(re - rs);
  float rdeg = (deg > 0.f) ? 1.0f / deg : 0.0f;
  float2 f = *reinterpret_cast<const float2*>(
      feat + (size_t)node * IN_DIM + lane * 2);
  float x0 = (f.x + (a0.x + a1.x) * rdeg) * 0.5f;
  float x1 = (f.y + (a0.y + a1.y) * rdeg) * 0.5f;
  x[(size_t)node * (IN_DIM / 2) + lane] = __floats2half2_rn(x0, x1);
}

// ---------------------------------------------------------------------------
// Kernel 6: MFMA GEMM out = relu(x @ W). Proven round 5; nt stores added.
// C/D layout (m89-verified): col=lane&15, row=(lane>>4)*4+reg.
// ---------------------------------------------------------------------------
__global__ __launch_bounds__(256) void mfma_gemm(
    const _Float16* __restrict__ x, const float* __restrict__ W,
    float* __restrict__ out) {
  __shared__ _Float16 WT[OUT_DIM * WT_STRIDE];  // 68 KiB -> 2 blocks/CU

  const int tid = threadIdx.x;
  {
    const int n = tid;
#pragma unroll
    for (int k = 0; k < IN_DIM; k += 4) {
      f16x4 v;
      v.x = (_Float16)W[(k + 0) * OUT_DIM + n];
      v.y = (_Float16)W[(k + 1) * OUT_DIM + n];
      v.z = (_Float16)W[(k + 2) * OUT_DIM + n];
      v.w = (_Float16)W[(k + 3) * OUT_DIM + n];
      *reinterpret_cast<f16x4*>(&WT[n * WT_STRIDE + k]) = v;
    }
  }
  __syncthreads();

  const int wave = tid >> 6;
  const int lane = tid & 63;
  const int m = lane & 15;
  const int g = lane >> 4;
  const long row_base = (long)blockIdx.x * 128 + wave * 32;

  f16x8 a[2][4];
#pragma unroll
  for (int rt = 0; rt < 2; ++rt) {
    long row = row_base + rt * 16 + m;
#pragma unroll
    for (int kt = 0; kt < 4; ++kt) {
      if (row < N_NODES) {
        a[rt][kt] = *reinterpret_cast<const f16x8*>(
            x + row * IN_DIM + kt * 32 + g * 8);
      } else {
        a[rt][kt] = f16x8{};
      }
    }
  }

#pragma unroll
  for (int nt = 0; nt < 16; ++nt) {
    f16x8 b[4];
#pragma unroll
    for (int kt = 0; kt < 4; ++kt) {
      b[kt] = *reinterpret_cast<const f16x8*>(
          &WT[(nt * 16 + m) * WT_STRIDE + kt * 32 + g * 8]);
    }
    f32x4 acc0 = {0.f, 0.f, 0.f, 0.f};
    f32x4 acc1 = {0.f, 0.f, 0.f, 0.f};
#pragma unroll
    for (int kt = 0; kt < 4; ++kt) {
      acc0 = __builtin_amdgcn_mfma_f32_16x16x32_f16(a[0][kt], b[kt], acc0, 0, 0, 0);
      acc1 = __builtin_amdgcn_mfma_f32_16x16x32_f16(a[1][kt], b[kt], acc1, 0, 0, 0);
    }
    const int col = nt * 16 + m;
#pragma unroll
    for (int j = 0; j < 4; ++j) {
      long r0 = row_base + g * 4 + j;
      long r1 = row_base + 16 + g * 4 + j;
      if (r0 < N_NODES)
        __builtin_nontemporal_store(fmaxf(acc0[j], 0.f),
                                    &out[r0 * OUT_DIM + col]);
      if (r1 < N_NODES)
        __builtin_nontemporal_store(fmaxf(acc1[j], 0.f),
                                    &out[r1 * OUT_DIM + col]);
    }
  }
}

extern "C" void kernel_launch(void* const* d_in, const int* in_sizes, int n_in,
                              void* d_out, int out_size, void* d_ws,
                              size_t ws_size, hipStream_t stream) {
  const float* feat = (const float*)d_in[0];
  const float* W = (const float*)d_in[1];
  const int* src = (const int*)d_in[2];
  const int* dst = (const int*)d_in[3];
  float* out = (float*)d_out;

  // Workspace (29.2 MB; round 5 proved ws >= 29.6 MB).
  // slot aliases the front of x: slot dies (scatter) before x is born
  // (aggregate) — stream-serial, safe.
  char* p = (char*)d_ws;
  __half* x = (__half*)p;    p += (size_t)N_NODES * IN_DIM * 2;  // 12.8 MB
  int* slot = (int*)x;                                           // 3.2 MB alias
  int* esrc = (int*)p;       p += (size_t)N_EDGES * 4;           // 3.2 MB
  int* hist = (int*)p;       p += (size_t)N_NODES * 4;           // 200 KB
  int* row_start = (int*)p;  p += (size_t)(N_NODES + 1) * 4;
  int* bsum = (int*)p;       p += 256 * 4;
  p = (char*)(((uintptr_t)p + 15) & ~(uintptr_t)15);
  __half* feat16 = (__half*)p;
  size_t need_f16 =
      ((char*)feat16 - (char*)d_ws) + (size_t)N_NODES * IN_DIM * 2;
  const bool f16_path = (ws_size >= need_f16);

  hipMemsetAsync(hist, 0, (size_t)N_NODES * 4, stream);

  const int eblocks = N_EDGES / 256;  // 3125, exact
  hist_cast<<<eblocks, 256, 0, stream>>>(dst, feat,
                                         f16_path ? feat16 : nullptr, hist,
                                         slot);
  scan_block<<<SCAN_BLOCKS, 256, 0, stream>>>(hist, row_start, bsum);
  scan_add<<<SCAN_BLOCKS, 256, 0, stream>>>(bsum, row_start);
  scatter_kernel<<<eblocks, 256, 0, stream>>>(src, dst, row_start, slot, esrc);
  if (f16_path) {
    aggregate_f16<<<(N_NODES + 3) / 4, 256, 0, stream>>>(feat, feat16, esrc,
                                                         row_start,
                                                         (__half2*)x);
  } else {
    aggregate_f32<<<(N_NODES + 3) / 4, 256, 0, stream>>>(feat, esrc, row_start,
                                                         (__half2*)x);
  }
  mfma_gemm<<<(N_NODES + 127) / 128, 256, 0, stream>>>(
      (const _Float16*)x, W, out);
}